// Round 1
// baseline (665.985 us; speedup 1.0000x reference)
//
#include <hip/hip_runtime.h>
#include <stdint.h>

// ---------------- problem constants ----------------
#define K_TOTAL   98304u     // 32 * 512 * 6
#define EMA_RATE  0.003f

// ---------------- select config ----------------
#define SBINS      16384     // sample histogram bins (top 14 bits of key)
#define SBIN_SHIFT 18
#define SAMPLE_VEC 131072    // float4s sampled = 524288 floats (1/48 of data)
#define STARGET    8192u     // sample count above threshold (~4x K when scaled)
#define SMP_BLOCKS 128

#define P2_BINS    4096      // candidate histogram bins
#define P2_SHIFT   12        // bin width = 4096 keys
#define LCAP       512       // per-block LDS candidate staging (exp ~192/block)
#define CAP2       65536u    // final-bin candidate cap
#define EQCAP      256       // tie buffer

#define MP_BLOCKS  2048      // 2048 blocks * 256 thr = 8 blocks/CU exactly
                             // nvec / (2048*256) = 12 float4 per thread

typedef float v4f __attribute__((ext_vector_type(4)));

// monotone float->uint key: order(key) == order(float)
__device__ __forceinline__ unsigned f2key(float x) {
    unsigned u = __float_as_uint(x);
    return (u & 0x80000000u) ? ~u : (u | 0x80000000u);
}
__device__ __forceinline__ float key2f(unsigned key) {
    unsigned u = (key & 0x80000000u) ? (key & 0x7FFFFFFFu) : ~key;
    return __uint_as_float(u);
}

// ---------------- S1: sample histogram + fused last-block scan -------------
// 128 blocks histogram the first 2 MB into a 16384-bin global hist (device
// atomics); the last block to finish (ticket election) pulls the hist back
// via atomic reads (no stale-L2 hazard) and scans descending for the base key.
__global__ __launch_bounds__(256) void sample_kernel(
        const float4* __restrict__ in, unsigned* __restrict__ shist,
        unsigned* __restrict__ done, unsigned* __restrict__ res) {
    __shared__ unsigned h[SBINS];            // 64 KB
    __shared__ unsigned psum[256];
    __shared__ unsigned lastS;
    int t = threadIdx.x;
    for (int i = t; i < SBINS; i += 256) h[i] = 0;
    __syncthreads();
    unsigned tid = blockIdx.x * 256 + t;
    unsigned nth = gridDim.x * 256;          // 32768; SAMPLE_VEC/nth = 4 exact
    float4 v[4];
    #pragma unroll
    for (int u = 0; u < 4; ++u) v[u] = in[tid + u * nth];
    #pragma unroll
    for (int u = 0; u < 4; ++u) {
        atomicAdd(&h[f2key(v[u].x) >> SBIN_SHIFT], 1u);
        atomicAdd(&h[f2key(v[u].y) >> SBIN_SHIFT], 1u);
        atomicAdd(&h[f2key(v[u].z) >> SBIN_SHIFT], 1u);
        atomicAdd(&h[f2key(v[u].w) >> SBIN_SHIFT], 1u);
    }
    __syncthreads();
    for (int i = t; i < SBINS; i += 256) {
        unsigned c = h[i];
        if (c) atomicAdd(&shist[i], c);
    }
    __threadfence();                          // release our hist atomics
    __syncthreads();
    if (t == 0) {
        unsigned d = atomicAdd(done, 1u);
        lastS = (d == gridDim.x - 1) ? 1u : 0u;
    }
    __syncthreads();
    if (!lastS) return;                       // uniform per block -> barrier-safe

    // ---- fused sample_scan (256 threads, 64 bins/thread, descending) ----
    for (int i = t; i < SBINS; i += 256) h[i] = atomicAdd(&shist[i], 0u);
    __syncthreads();
    const int GB = SBINS / 256;               // 64
    int hi = SBINS - 1 - t * GB;
    unsigned s = 0;
    for (int j = 0; j < GB; ++j) s += h[hi - j];
    psum[t] = s;
    __syncthreads();
    for (int off = 1; off < 256; off <<= 1) {
        unsigned o = (t >= off) ? psum[t - off] : 0u;
        __syncthreads();
        psum[t] += o;
        __syncthreads();
    }
    unsigned cum = psum[t] - s;               // samples strictly above my group
    for (int j = 0; j < GB; ++j) {
        unsigned c = h[hi - j];
        if (cum < STARGET && cum + c >= STARGET) {
            unsigned bin = (unsigned)(hi - j);
            unsigned bb = (bin > 0) ? bin - 1 : 0;   // one extra margin bin
            res[0] = bb << SBIN_SHIFT;               // base key
        }
        cum += c;
    }
}

// ---------------- P2 fused: zero-out + compact + cand-hist + find_g --------
// One streaming pass: read in[], nontemporal-store zeros to out[], stage
// candidates in LDS (flush per block), histogram candidates directly into
// global ghist (device atomics). Last-finishing block scans ghist -> res2.
#define PROCESS_VEC(vv, jvec)                                                \
    {                                                                        \
        unsigned idx0_ = 4u * (jvec);                                        \
        float xs_[4] = {(vv).x, (vv).y, (vv).z, (vv).w};                     \
        _Pragma("unroll")                                                    \
        for (int c_ = 0; c_ < 4; ++c_) {                                     \
            unsigned key_ = f2key(xs_[c_]);                                  \
            if (key_ >= base) {               /* ~1.7% taken */              \
                unsigned g_ = (key_ - base) >> P2_SHIFT;                     \
                if (g_ > P2_BINS - 1) g_ = P2_BINS - 1;                      \
                atomicAdd(&ghist[g_], 1u);                                   \
                unsigned p_ = atomicAdd(&lcnt, 1u);                          \
                if (p_ < LCAP) {                                             \
                    ((float*)ubuf)[p_] = xs_[c_];                            \
                    ubuf[LCAP + p_] = idx0_ + (unsigned)c_;                  \
                } else {                      /* overflow fallback */        \
                    unsigned q_ = atomicAdd(gcnt, 1u);                       \
                    if (q_ < cap) { cval[q_] = xs_[c_]; cidx[q_] = idx0_ + (unsigned)c_; } \
                }                                                            \
            }                                                                \
        }                                                                    \
    }

__global__ __launch_bounds__(256, 8) void main_pass_kernel(
        const float4* __restrict__ in, float4* __restrict__ outv,
        const unsigned* __restrict__ res,
        float* __restrict__ cval, unsigned* __restrict__ cidx,
        unsigned* __restrict__ gcnt, unsigned* __restrict__ ghist,
        unsigned* __restrict__ done, unsigned* __restrict__ res2,
        unsigned cap, unsigned nvec) {
    // ubuf: staging (lval = ubuf[0..LCAP) as float, lidx = ubuf[LCAP..2*LCAP))
    // then reused as the ghist read buffer by the last block. 16 KB.
    __shared__ unsigned ubuf[P2_BINS];
    __shared__ unsigned psum[256];
    __shared__ unsigned lcnt, lbase, lastS;
    int t = threadIdx.x;
    if (t == 0) lcnt = 0;
    __syncthreads();
    unsigned base = res[0];
    unsigned tid = blockIdx.x * 256 + t;
    unsigned nth = gridDim.x * 256;          // 524288; nvec/nth = 12 exact
    const v4f z4 = {0.f, 0.f, 0.f, 0.f};

    unsigned i0 = tid;
    unsigned nb = nvec / (4u * nth);         // 3 batches of 4 for our shape
    for (unsigned b = 0; b < nb; ++b) {
        float4 v[4];
        #pragma unroll
        for (int u = 0; u < 4; ++u) v[u] = in[i0 + u * nth];       // 4 in flight
        #pragma unroll
        for (int u = 0; u < 4; ++u)                                // fused zero
            __builtin_nontemporal_store(z4, (v4f*)(outv + (i0 + u * nth)));
        #pragma unroll
        for (int u = 0; u < 4; ++u) PROCESS_VEC(v[u], i0 + u * nth);
        i0 += 4u * nth;
    }
    for (; i0 < nvec; i0 += nth) {           // generic tail (empty for 25165824)
        float4 v = in[i0];
        __builtin_nontemporal_store(z4, (v4f*)(outv + i0));
        PROCESS_VEC(v, i0);
    }

    // ---- flush block staging to global candidate list ----
    __syncthreads();
    unsigned n = min(lcnt, (unsigned)LCAP);
    if (t == 0) lbase = atomicAdd(gcnt, n);
    __syncthreads();
    for (unsigned j = t; j < n; j += 256) {
        unsigned p = lbase + j;
        if (p < cap) { cval[p] = ((float*)ubuf)[j]; cidx[p] = ubuf[LCAP + j]; }
    }

    // ---- ticket election: last block to arrive does find_g ----
    __threadfence();
    __syncthreads();
    if (t == 0) {
        unsigned d = atomicAdd(done, 1u);
        lastS = (d == gridDim.x - 1) ? 1u : 0u;
    }
    __syncthreads();
    if (!lastS) return;                       // uniform per block

    for (int i = t; i < P2_BINS; i += 256) ubuf[i] = atomicAdd(&ghist[i], 0u);
    __syncthreads();
    const int GB = P2_BINS / 256;             // 16 bins/thread, descending
    int hi = P2_BINS - 1 - t * GB;
    unsigned s = 0;
    #pragma unroll
    for (int j = 0; j < GB; ++j) s += ubuf[hi - j];
    psum[t] = s;
    __syncthreads();
    for (int off = 1; off < 256; off <<= 1) {
        unsigned o = (t >= off) ? psum[t - off] : 0u;
        __syncthreads();
        psum[t] += o;
        __syncthreads();
    }
    unsigned cum = psum[t] - s;
    for (int j = 0; j < GB; ++j) {
        unsigned c = ubuf[hi - j];
        if (cum < K_TOTAL && cum + c >= K_TOTAL) {
            res2[0] = (unsigned)(hi - j);     // g*
            res2[1] = K_TOTAL - cum;          // need2 inside bin g*
        }
        cum += c;
    }
}

// ---------------- C3: scatter definite winners, compact bin-g* -------------
__global__ __launch_bounds__(256) void scatter_kernel(
        const float* __restrict__ cval, const unsigned* __restrict__ cidx,
        const unsigned* __restrict__ gcnt, const unsigned* __restrict__ res,
        const unsigned* __restrict__ res2,
        float* __restrict__ cval2, unsigned* __restrict__ cidx2,
        unsigned* __restrict__ cnt2, unsigned cap,
        float* __restrict__ out) {
    unsigned nc = min(*gcnt, cap);
    unsigned base = res[0];
    unsigned gstar = res2[0];
    unsigned tid = blockIdx.x * 256 + threadIdx.x;
    unsigned nth = gridDim.x * 256;
    for (unsigned i0 = tid; i0 < nc; i0 += 4 * nth) {
        float v[4];
        #pragma unroll
        for (int u = 0; u < 4; ++u) {
            unsigned j = i0 + u * nth;
            v[u] = (j < nc) ? cval[j] : -1e30f;
        }
        #pragma unroll
        for (int u = 0; u < 4; ++u) {
            unsigned j = i0 + u * nth;
            if (j < nc) {
                unsigned g = (f2key(v[u]) - base) >> P2_SHIFT;
                if (g > P2_BINS - 1) g = P2_BINS - 1;
                if (g > gstar) {
                    out[cidx[j]] = fmaxf(v[u], 0.0f);    // definite winner
                } else if (g == gstar) {
                    unsigned p = atomicAdd(cnt2, 1u);
                    if (p < CAP2) { cval2[p] = v[u]; cidx2[p] = cidx[j]; }
                }
            }
        }
    }
}

// ---------------- C4: exact select in 4096-key range, ties, EMA ------------
__global__ __launch_bounds__(256) void final_kernel(
        const float* __restrict__ cval2, const unsigned* __restrict__ cidx2,
        const unsigned* __restrict__ cnt2,
        const unsigned* __restrict__ res, const unsigned* __restrict__ res2,
        float* __restrict__ out,
        const float* __restrict__ thr_in, float* __restrict__ thr_out) {
    __shared__ unsigned h[1 << P2_SHIFT];     // one bin per exact key
    __shared__ unsigned psum[256];
    __shared__ unsigned eqidx[EQCAP];
    __shared__ unsigned eqcnt;
    __shared__ unsigned sh_low, sh_need3;
    const int NB = 1 << P2_SHIFT;             // 4096
    int t = threadIdx.x;
    unsigned nc2   = min(*cnt2, CAP2);
    unsigned base3 = res[0] + (res2[0] << P2_SHIFT);
    unsigned need2 = res2[1];

    for (int i = t; i < NB; i += 256) h[i] = 0;
    if (t == 0) eqcnt = 0;
    __syncthreads();
    for (unsigned i = t; i < nc2; i += 256) {
        unsigned low = f2key(cval2[i]) - base3;
        if (low > (unsigned)(NB - 1)) low = NB - 1;
        atomicAdd(&h[low], 1u);
    }
    __syncthreads();

    const int GB = NB / 256;                  // 16 keys/thread, descending
    int hi = NB - 1 - t * GB;
    unsigned s = 0;
    for (int j = 0; j < GB; ++j) s += h[hi - j];
    psum[t] = s;
    __syncthreads();
    for (int off = 1; off < 256; off <<= 1) {
        unsigned o = (t >= off) ? psum[t - off] : 0u;
        __syncthreads();
        psum[t] += o;
        __syncthreads();
    }
    unsigned cum = psum[t] - s;
    for (int j = 0; j < GB; ++j) {
        unsigned c = h[hi - j];
        if (cum < need2 && cum + c >= need2) {
            sh_low = (unsigned)(hi - j);
            sh_need3 = need2 - cum;           // ties to accept at kth key
        }
        cum += c;
    }
    __syncthreads();
    unsigned kth_key = base3 + sh_low;
    unsigned need3   = sh_need3;

    for (unsigned i = t; i < nc2; i += 256) {
        float x = cval2[i];
        unsigned key = f2key(x);
        if (key > kth_key) {
            out[cidx2[i]] = fmaxf(x, 0.0f);
        } else if (key == kth_key) {
            unsigned p = atomicAdd(&eqcnt, 1u);
            if (p < EQCAP) eqidx[p] = cidx2[i];
        }
    }
    __syncthreads();

    // tie-break: lax.top_k picks lowest flat indices first
    unsigned ne = min(eqcnt, (unsigned)EQCAP);
    float vv = key2f(kth_key);
    for (unsigned e = t; e < ne; e += 256) {
        unsigned my = eqidx[e];
        unsigned rank = 0;
        for (unsigned f = 0; f < ne; ++f) rank += (eqidx[f] < my) ? 1u : 0u;
        if (rank < need3) out[my] = fmaxf(vv, 0.0f);
    }

    if (t == 0) {
        float mink = fmaxf(vv, 0.0f);         // relu(k-th largest)
        thr_out[0] = (1.0f - EMA_RATE) * thr_in[0] + EMA_RATE * mink;
    }
}

// ---------------- launch ----------------
extern "C" void kernel_launch(void* const* d_in, const int* in_sizes, int n_in,
                              void* d_out, int out_size, void* d_ws, size_t ws_size,
                              hipStream_t stream) {
    const float* feat   = (const float*)d_in[0];
    const float* thr_in = (const float*)d_in[1];
    float* out = (float*)d_out;
    int N    = in_sizes[0];      // 25165824
    int nvec = N / 4;

    // ---- workspace layout ----
    uint8_t* w = (uint8_t*)d_ws;
    unsigned* shist = (unsigned*)w;                        // 64 KB
    unsigned* ghist = (unsigned*)(w + (64 << 10));         // 16 KB
    unsigned* ctr   = (unsigned*)(w + (80 << 10));         // counters/res block
    unsigned* gcnt  = ctr + 0;
    unsigned* cnt2  = ctr + 1;
    unsigned* done1 = ctr + 2;    // sample ticket
    unsigned* done2 = ctr + 3;    // main-pass ticket
    unsigned* res   = ctr + 4;    // res[0] = base key
    unsigned* res2  = ctr + 8;    // res2[0] = g*, res2[1] = need2

    size_t cand_off = (size_t)1 << 20;
    size_t avail    = (ws_size > cand_off + (CAP2 * 8 + 4096))
                        ? (ws_size - cand_off - CAP2 * 8 - 4096) / 8 : 0;
    unsigned cap = (unsigned)((avail < (size_t)(4u << 20)) ? avail : (size_t)(4u << 20));
    float*    cval  = (float*)(w + cand_off);
    unsigned* cidx  = (unsigned*)(w + cand_off + (size_t)cap * 4);
    float*    cval2 = (float*)(w + cand_off + (size_t)cap * 8);
    unsigned* cidx2 = (unsigned*)(w + cand_off + (size_t)cap * 8 + CAP2 * 4);

    // zero hists + counters only; output zeroing is fused into main_pass
    hipMemsetAsync(d_ws, 0, (80 << 10) + 64, stream);

    sample_kernel   <<<SMP_BLOCKS, 256, 0, stream>>>((const float4*)feat,
                                                     shist, done1, res);
    main_pass_kernel<<<MP_BLOCKS, 256, 0, stream>>>((const float4*)feat,
                                                    (float4*)out, res,
                                                    cval, cidx, gcnt, ghist,
                                                    done2, res2, cap,
                                                    (unsigned)nvec);
    scatter_kernel  <<<128, 256, 0, stream>>>(cval, cidx, gcnt, res, res2,
                                              cval2, cidx2, cnt2, cap, out);
    final_kernel    <<<1,   256, 0, stream>>>(cval2, cidx2, cnt2, res, res2,
                                              out, thr_in, out + N);
}

// Round 3
// 302.530 us; speedup vs baseline: 2.2014x; 2.2014x over previous
//
#include <hip/hip_runtime.h>
#include <stdint.h>

// ---------------- problem constants ----------------
#define K_TOTAL   98304u     // 32 * 512 * 6
#define EMA_RATE  0.003f

// ---------------- select config ----------------
#define SBINS      16384     // sample histogram bins (top 14 bits of key)
#define SBIN_SHIFT 18
#define SAMPLE_VEC 131072    // float4s sampled = 524288 floats (1/48 of data)
#define STARGET    8192u     // sample count above threshold (~4x K when scaled)
#define SMP_BLOCKS 128

#define P2_BINS    4096      // candidate histogram bins
#define P2_SHIFT   12        // bin width = 4096 keys
#define LCAP       1024      // per-block LDS candidate staging (~200 expected)
#define CAP2       65536u    // final-bin candidate cap
#define EQCAP      256       // tie buffer

#define FILL_BLOCKS 512      // 512 blocks * 256 thr * 48 f4 = 6291456 = nvec
#define FILL_PT     48
#define MP_BLOCKS   2048     // 2048 * 256 * 12 = 6291456 = nvec exactly
#define MP_BATCH    6        // loads in flight per batch (2 batches)

// monotone float->uint key: order(key) == order(float)
__device__ __forceinline__ unsigned f2key(float x) {
    unsigned u = __float_as_uint(x);
    return (u & 0x80000000u) ? ~u : (u | 0x80000000u);
}
__device__ __forceinline__ float key2f(unsigned key) {
    unsigned u = (key & 0x80000000u) ? (key & 0x7FFFFFFFu) : ~key;
    return __uint_as_float(u);
}

// ---- A: zero-fill out (plain cached float4 stores, block-contiguous) ------
//      + blocks 0..127 sample-histogram the first 2 MB (iid data)
//      + last-finishing block (ticket) scans hist descending -> base key
__global__ __launch_bounds__(256) void fill_sample_kernel(
        const float4* __restrict__ in, float4* __restrict__ outv,
        unsigned* __restrict__ shist, unsigned* __restrict__ done,
        unsigned* __restrict__ res, unsigned nvec) {
    __shared__ unsigned h[SBINS];            // 64 KB (also reused by scan)
    __shared__ unsigned psum[256];
    __shared__ unsigned lastS;
    int t = threadIdx.x;
    bool sampler = (blockIdx.x < SMP_BLOCKS);   // uniform per block

    if (sampler) {
        for (int i = t; i < SBINS; i += 256) h[i] = 0;
        __syncthreads();
    }

    // ---- contiguous zero-fill: block b owns [b*12288, (b+1)*12288) f4 ----
    const float4 z4 = make_float4(0.f, 0.f, 0.f, 0.f);
    unsigned slice = blockIdx.x * (256u * FILL_PT);
    #pragma unroll
    for (int k = 0; k < FILL_PT; ++k) {
        unsigned j = slice + (unsigned)k * 256u + (unsigned)t;
        if (j < nvec) outv[j] = z4;
    }

    // ---- sampling (first 128 blocks only) ----
    if (sampler) {
        unsigned tid = blockIdx.x * 256 + t;
        unsigned snth = SMP_BLOCKS * 256;    // 32768; SAMPLE_VEC/snth = 4 exact
        float4 v[4];
        #pragma unroll
        for (int u = 0; u < 4; ++u) v[u] = in[tid + u * snth];
        #pragma unroll
        for (int u = 0; u < 4; ++u) {
            atomicAdd(&h[f2key(v[u].x) >> SBIN_SHIFT], 1u);
            atomicAdd(&h[f2key(v[u].y) >> SBIN_SHIFT], 1u);
            atomicAdd(&h[f2key(v[u].z) >> SBIN_SHIFT], 1u);
            atomicAdd(&h[f2key(v[u].w) >> SBIN_SHIFT], 1u);
        }
        __syncthreads();
        for (int i = t; i < SBINS; i += 256) {
            unsigned c = h[i];
            if (c) atomicAdd(&shist[i], c);
        }
    }

    // ---- ticket election: last block to arrive scans hist -> res[0] ----
    __threadfence();                          // release hist atomics / fills
    __syncthreads();
    if (t == 0) {
        unsigned d = atomicAdd(done, 1u);
        lastS = (d == gridDim.x - 1) ? 1u : 0u;
    }
    __syncthreads();
    if (!lastS) return;                       // uniform per block

    for (int i = t; i < SBINS; i += 256) h[i] = atomicAdd(&shist[i], 0u);
    __syncthreads();
    const int GB = SBINS / 256;               // 64 bins/thread, descending
    int hi = SBINS - 1 - t * GB;
    unsigned s = 0;
    for (int j = 0; j < GB; ++j) s += h[hi - j];
    psum[t] = s;
    __syncthreads();
    for (int off = 1; off < 256; off <<= 1) {
        unsigned o = (t >= off) ? psum[t - off] : 0u;
        __syncthreads();
        psum[t] += o;
        __syncthreads();
    }
    unsigned cum = psum[t] - s;               // samples strictly above my group
    for (int j = 0; j < GB; ++j) {
        unsigned c = h[hi - j];
        if (cum < STARGET && cum + c >= STARGET) {
            unsigned bin = (unsigned)(hi - j);
            unsigned bb = (bin > 0) ? bin - 1 : 0;   // one extra margin bin
            res[0] = bb << SBIN_SHIFT;               // base key
        }
        cum += c;
    }
}

// ---------------- P2: single full-data pass — compact candidates -----------
// (round-0 proven structure: read-only + LDS staging; no out stores,
//  no global hist atomics. Unconditional loads: grid divides nvec exactly.)
__global__ __launch_bounds__(256) void main_pass_kernel(
        const float4* __restrict__ in, const unsigned* __restrict__ res,
        float* __restrict__ cval, unsigned* __restrict__ cidx,
        unsigned* __restrict__ gcnt, unsigned cap, unsigned nvec) {
    __shared__ float    lval[LCAP];
    __shared__ unsigned lidx[LCAP];
    __shared__ unsigned lcnt, lbase;
    if (threadIdx.x == 0) lcnt = 0;
    __syncthreads();
    unsigned base = res[0];
    unsigned tid = blockIdx.x * 256 + threadIdx.x;
    unsigned nth = gridDim.x * 256;          // 524288; nvec/(6*nth) = 2 exact
    unsigned i0 = tid;
    unsigned nb = nvec / (MP_BATCH * nth);
    for (unsigned b = 0; b < nb; ++b) {
        float4 v[MP_BATCH];
        #pragma unroll
        for (int u = 0; u < MP_BATCH; ++u) v[u] = in[i0 + u * nth];  // 6 in flight
        #pragma unroll
        for (int u = 0; u < MP_BATCH; ++u) {
            unsigned j = i0 + u * nth;
            unsigned idx = 4u * j;
            float xs[4] = {v[u].x, v[u].y, v[u].z, v[u].w};
            #pragma unroll
            for (int c = 0; c < 4; ++c) {
                unsigned key = f2key(xs[c]);
                if (key >= base) {                // ~1.7% taken
                    unsigned p = atomicAdd(&lcnt, 1u);
                    if (p < LCAP) { lval[p] = xs[c]; lidx[p] = idx + c; }
                    else {                        // overflow fallback
                        unsigned q = atomicAdd(gcnt, 1u);
                        if (q < cap) { cval[q] = xs[c]; cidx[q] = idx + c; }
                    }
                }
            }
        }
        i0 += MP_BATCH * nth;
    }
    for (; i0 < nvec; i0 += nth) {           // generic tail (empty here)
        float4 v = in[i0];
        unsigned idx = 4u * i0;
        float xs[4] = {v.x, v.y, v.z, v.w};
        #pragma unroll
        for (int c = 0; c < 4; ++c) {
            unsigned key = f2key(xs[c]);
            if (key >= base) {
                unsigned p = atomicAdd(&lcnt, 1u);
                if (p < LCAP) { lval[p] = xs[c]; lidx[p] = idx + c; }
                else {
                    unsigned q = atomicAdd(gcnt, 1u);
                    if (q < cap) { cval[q] = xs[c]; cidx[q] = idx + c; }
                }
            }
        }
    }
    __syncthreads();
    unsigned n = min(lcnt, (unsigned)LCAP);
    if (threadIdx.x == 0) lbase = atomicAdd(gcnt, n);
    __syncthreads();
    for (unsigned j = threadIdx.x; j < n; j += 256) {
        unsigned p = lbase + j;
        if (p < cap) { cval[p] = lval[j]; cidx[p] = lidx[j]; }
    }
}

// ---------------- CH: histogram the compacted candidates -------------------
__global__ __launch_bounds__(256) void cand_hist_kernel(
        const float* __restrict__ cval, const unsigned* __restrict__ gcnt,
        const unsigned* __restrict__ res, unsigned* __restrict__ ghist,
        unsigned cap) {
    __shared__ unsigned h[P2_BINS];
    for (int i = threadIdx.x; i < P2_BINS; i += 256) h[i] = 0;
    __syncthreads();
    unsigned nc = min(*gcnt, cap);
    unsigned base = res[0];
    unsigned tid = blockIdx.x * 256 + threadIdx.x;
    unsigned nth = gridDim.x * 256;
    for (unsigned i0 = tid; i0 < nc; i0 += 4 * nth) {
        float v[4];
        #pragma unroll
        for (int u = 0; u < 4; ++u) {
            unsigned j = i0 + u * nth;
            v[u] = (j < nc) ? cval[j] : -1e30f;
        }
        #pragma unroll
        for (int u = 0; u < 4; ++u) {
            unsigned j = i0 + u * nth;
            if (j < nc) {
                unsigned g = (f2key(v[u]) - base) >> P2_SHIFT;
                if (g > P2_BINS - 1) g = P2_BINS - 1;
                atomicAdd(&h[g], 1u);
            }
        }
    }
    __syncthreads();
    for (int i = threadIdx.x; i < P2_BINS; i += 256) {
        unsigned c = h[i];
        if (c) atomicAdd(&ghist[i], c);
    }
}

// ---------------- C2: scan candidate hist -> bin g*, need2 -----------------
__global__ __launch_bounds__(1024) void find_g_kernel(
        const unsigned* __restrict__ ghist, unsigned* __restrict__ res2) {
    __shared__ unsigned psum[1024];
    const int T = 1024;
    const int GB = P2_BINS / T;               // 4 bins/thread, descending
    int t = threadIdx.x;
    int hi = P2_BINS - 1 - t * GB;
    unsigned c[GB];
    #pragma unroll
    for (int j = 0; j < GB; ++j) c[j] = ghist[hi - j];
    unsigned s = 0;
    #pragma unroll
    for (int j = 0; j < GB; ++j) s += c[j];
    psum[t] = s;
    __syncthreads();
    for (int off = 1; off < T; off <<= 1) {
        unsigned o = (t >= off) ? psum[t - off] : 0u;
        __syncthreads();
        psum[t] += o;
        __syncthreads();
    }
    unsigned cum = psum[t] - s;
    for (int j = 0; j < GB; ++j) {
        if (cum < K_TOTAL && cum + c[j] >= K_TOTAL) {
            res2[0] = (unsigned)(hi - j);     // g*
            res2[1] = K_TOTAL - cum;          // need2 inside bin g*
        }
        cum += c[j];
    }
}

// ---------------- C3: scatter definite winners, compact bin-g* -------------
__global__ __launch_bounds__(256) void scatter_kernel(
        const float* __restrict__ cval, const unsigned* __restrict__ cidx,
        const unsigned* __restrict__ gcnt, const unsigned* __restrict__ res,
        const unsigned* __restrict__ res2,
        float* __restrict__ cval2, unsigned* __restrict__ cidx2,
        unsigned* __restrict__ cnt2, unsigned cap,
        float* __restrict__ out) {
    unsigned nc = min(*gcnt, cap);
    unsigned base = res[0];
    unsigned gstar = res2[0];
    unsigned tid = blockIdx.x * 256 + threadIdx.x;
    unsigned nth = gridDim.x * 256;
    for (unsigned i0 = tid; i0 < nc; i0 += 4 * nth) {
        float v[4];
        #pragma unroll
        for (int u = 0; u < 4; ++u) {
            unsigned j = i0 + u * nth;
            v[u] = (j < nc) ? cval[j] : -1e30f;
        }
        #pragma unroll
        for (int u = 0; u < 4; ++u) {
            unsigned j = i0 + u * nth;
            if (j < nc) {
                unsigned g = (f2key(v[u]) - base) >> P2_SHIFT;
                if (g > P2_BINS - 1) g = P2_BINS - 1;
                if (g > gstar) {
                    out[cidx[j]] = fmaxf(v[u], 0.0f);    // definite winner
                } else if (g == gstar) {
                    unsigned p = atomicAdd(cnt2, 1u);
                    if (p < CAP2) { cval2[p] = v[u]; cidx2[p] = cidx[j]; }
                }
            }
        }
    }
}

// ---------------- C4: exact select in 4096-key range, ties, EMA ------------
__global__ __launch_bounds__(256) void final_kernel(
        const float* __restrict__ cval2, const unsigned* __restrict__ cidx2,
        const unsigned* __restrict__ cnt2,
        const unsigned* __restrict__ res, const unsigned* __restrict__ res2,
        float* __restrict__ out,
        const float* __restrict__ thr_in, float* __restrict__ thr_out) {
    __shared__ unsigned h[1 << P2_SHIFT];     // one bin per exact key
    __shared__ unsigned psum[256];
    __shared__ unsigned eqidx[EQCAP];
    __shared__ unsigned eqcnt;
    __shared__ unsigned sh_low, sh_need3;
    const int NB = 1 << P2_SHIFT;             // 4096
    int t = threadIdx.x;
    unsigned nc2   = min(*cnt2, CAP2);
    unsigned base3 = res[0] + (res2[0] << P2_SHIFT);
    unsigned need2 = res2[1];

    for (int i = t; i < NB; i += 256) h[i] = 0;
    if (t == 0) eqcnt = 0;
    __syncthreads();
    for (unsigned i = t; i < nc2; i += 256) {
        unsigned low = f2key(cval2[i]) - base3;
        if (low > (unsigned)(NB - 1)) low = NB - 1;
        atomicAdd(&h[low], 1u);
    }
    __syncthreads();

    const int GB = NB / 256;                  // 16 keys/thread, descending
    int hi = NB - 1 - t * GB;
    unsigned s = 0;
    for (int j = 0; j < GB; ++j) s += h[hi - j];
    psum[t] = s;
    __syncthreads();
    for (int off = 1; off < 256; off <<= 1) {
        unsigned o = (t >= off) ? psum[t - off] : 0u;
        __syncthreads();
        psum[t] += o;
        __syncthreads();
    }
    unsigned cum = psum[t] - s;
    for (int j = 0; j < GB; ++j) {
        unsigned c = h[hi - j];
        if (cum < need2 && cum + c >= need2) {
            sh_low = (unsigned)(hi - j);
            sh_need3 = need2 - cum;           // ties to accept at kth key
        }
        cum += c;
    }
    __syncthreads();
    unsigned kth_key = base3 + sh_low;
    unsigned need3   = sh_need3;

    for (unsigned i = t; i < nc2; i += 256) {
        float x = cval2[i];
        unsigned key = f2key(x);
        if (key > kth_key) {
            out[cidx2[i]] = fmaxf(x, 0.0f);
        } else if (key == kth_key) {
            unsigned p = atomicAdd(&eqcnt, 1u);
            if (p < EQCAP) eqidx[p] = cidx2[i];
        }
    }
    __syncthreads();

    // tie-break: lax.top_k picks lowest flat indices first
    unsigned ne = min(eqcnt, (unsigned)EQCAP);
    float vv = key2f(kth_key);
    for (unsigned e = t; e < ne; e += 256) {
        unsigned my = eqidx[e];
        unsigned rank = 0;
        for (unsigned f = 0; f < ne; ++f) rank += (eqidx[f] < my) ? 1u : 0u;
        if (rank < need3) out[my] = fmaxf(vv, 0.0f);
    }

    if (t == 0) {
        float mink = fmaxf(vv, 0.0f);         // relu(k-th largest)
        thr_out[0] = (1.0f - EMA_RATE) * thr_in[0] + EMA_RATE * mink;
    }
}

// ---------------- launch ----------------
extern "C" void kernel_launch(void* const* d_in, const int* in_sizes, int n_in,
                              void* d_out, int out_size, void* d_ws, size_t ws_size,
                              hipStream_t stream) {
    const float* feat   = (const float*)d_in[0];
    const float* thr_in = (const float*)d_in[1];
    float* out = (float*)d_out;
    int N    = in_sizes[0];      // 25165824
    int nvec = N / 4;

    // ---- workspace layout ----
    uint8_t* w = (uint8_t*)d_ws;
    unsigned* shist = (unsigned*)w;                        // 64 KB
    unsigned* ghist = (unsigned*)(w + (64 << 10));         // 16 KB
    unsigned* ctr   = (unsigned*)(w + (80 << 10));         // counters/res block
    unsigned* gcnt  = ctr + 0;
    unsigned* cnt2  = ctr + 1;
    unsigned* done1 = ctr + 2;    // fill_sample ticket
    unsigned* res   = ctr + 4;    // res[0] = base key
    unsigned* res2  = ctr + 8;    // res2[0] = g*, res2[1] = need2

    size_t cand_off = (size_t)1 << 20;
    size_t avail    = (ws_size > cand_off + (CAP2 * 8 + 4096))
                        ? (ws_size - cand_off - CAP2 * 8 - 4096) / 8 : 0;
    unsigned cap = (unsigned)((avail < (size_t)(4u << 20)) ? avail : (size_t)(4u << 20));
    float*    cval  = (float*)(w + cand_off);
    unsigned* cidx  = (unsigned*)(w + cand_off + (size_t)cap * 4);
    float*    cval2 = (float*)(w + cand_off + (size_t)cap * 8);
    unsigned* cidx2 = (unsigned*)(w + cand_off + (size_t)cap * 8 + CAP2 * 4);

    // zero hists + counters only; output zeroing fused into fill_sample
    hipMemsetAsync(d_ws, 0, (80 << 10) + 64, stream);

    fill_sample_kernel<<<FILL_BLOCKS, 256, 0, stream>>>((const float4*)feat,
                                                        (float4*)out, shist,
                                                        done1, res,
                                                        (unsigned)nvec);
    main_pass_kernel  <<<MP_BLOCKS, 256, 0, stream>>>((const float4*)feat, res,
                                                      cval, cidx, gcnt, cap,
                                                      (unsigned)nvec);
    cand_hist_kernel  <<<128, 256, 0, stream>>>(cval, gcnt, res, ghist, cap);
    find_g_kernel     <<<1,  1024, 0, stream>>>(ghist, res2);
    scatter_kernel    <<<128, 256, 0, stream>>>(cval, cidx, gcnt, res, res2,
                                                cval2, cidx2, cnt2, cap, out);
    final_kernel      <<<1,   256, 0, stream>>>(cval2, cidx2, cnt2, res, res2,
                                                out, thr_in, out + N);
}

// Round 5
// 268.590 us; speedup vs baseline: 2.4796x; 1.1264x over previous
//
#include <hip/hip_runtime.h>
#include <stdint.h>

// ---------------- problem constants ----------------
#define K_TOTAL   98304u     // 32 * 512 * 6
#define EMA_RATE  0.003f

// ---------------- select config ----------------
#define SBINS      16384     // sample histogram bins (top 14 bits of key)
#define SBIN_SHIFT 18
#define SAMPLE_VEC 131072    // float4s sampled = 524288 floats (1/48 of data)
#define STARGET    8192u     // sample count above threshold (~4x K when scaled)
#define SMP_BLOCKS 128

#define P2_BINS    4096      // candidate histogram bins
#define P2_SHIFT   12        // bin width = 4096 keys
#define LCAP       1024      // per-block LDS candidate staging (~200 expected)
#define CAP2       65536u    // final-bin candidate cap
#define EQCAP      256       // tie buffer

#define MP_BLOCKS   2048     // 2048 * 256 * 12 = 6291456 = nvec exactly
#define MP_BATCH    6        // loads in flight per batch (2 batches)

// monotone float->uint key: order(key) == order(float)
__device__ __forceinline__ unsigned f2key(float x) {
    unsigned u = __float_as_uint(x);
    return (u & 0x80000000u) ? ~u : (u | 0x80000000u);
}
__device__ __forceinline__ float key2f(unsigned key) {
    unsigned u = (key & 0x80000000u) ? (key & 0x7FFFFFFFu) : ~key;
    return __uint_as_float(u);
}

// ---- S1: sample hist of first 2 MB + ticketed last-block scan -> res[0] ---
// 128 blocks = 1 per CU on half the chip; 64 KB LDS is fine here (proven r1/r3).
__global__ __launch_bounds__(256) void sample_kernel(
        const float4* __restrict__ in, unsigned* __restrict__ shist,
        unsigned* __restrict__ done, unsigned* __restrict__ res) {
    __shared__ unsigned h[SBINS];            // 64 KB (reused by the scan)
    __shared__ unsigned psum[256];
    __shared__ unsigned lastS;
    int t = threadIdx.x;
    for (int i = t; i < SBINS; i += 256) h[i] = 0;
    __syncthreads();
    unsigned tid = blockIdx.x * 256 + t;
    unsigned nth = SMP_BLOCKS * 256;         // 32768; SAMPLE_VEC/nth = 4 exact
    float4 v[4];
    #pragma unroll
    for (int u = 0; u < 4; ++u) v[u] = in[tid + u * nth];
    #pragma unroll
    for (int u = 0; u < 4; ++u) {
        atomicAdd(&h[f2key(v[u].x) >> SBIN_SHIFT], 1u);
        atomicAdd(&h[f2key(v[u].y) >> SBIN_SHIFT], 1u);
        atomicAdd(&h[f2key(v[u].z) >> SBIN_SHIFT], 1u);
        atomicAdd(&h[f2key(v[u].w) >> SBIN_SHIFT], 1u);
    }
    __syncthreads();
    for (int i = t; i < SBINS; i += 256) {
        unsigned c = h[i];
        if (c) atomicAdd(&shist[i], c);
    }
    __threadfence();                          // release hist atomics
    __syncthreads();
    if (t == 0) {
        unsigned d = atomicAdd(done, 1u);
        lastS = (d == gridDim.x - 1) ? 1u : 0u;
    }
    __syncthreads();
    if (!lastS) return;                       // uniform per block

    for (int i = t; i < SBINS; i += 256) h[i] = atomicAdd(&shist[i], 0u);
    __syncthreads();
    const int GB = SBINS / 256;               // 64 bins/thread, descending
    int hi = SBINS - 1 - t * GB;
    unsigned s = 0;
    for (int j = 0; j < GB; ++j) s += h[hi - j];
    psum[t] = s;
    __syncthreads();
    for (int off = 1; off < 256; off <<= 1) {
        unsigned o = (t >= off) ? psum[t - off] : 0u;
        __syncthreads();
        psum[t] += o;
        __syncthreads();
    }
    unsigned cum = psum[t] - s;               // samples strictly above my group
    for (int j = 0; j < GB; ++j) {
        unsigned c = h[hi - j];
        if (cum < STARGET && cum + c >= STARGET) {
            unsigned bin = (unsigned)(hi - j);
            unsigned bb = (bin > 0) ? bin - 1 : 0;   // one extra margin bin
            res[0] = bb << SBIN_SHIFT;               // base key
        }
        cum += c;
    }
}

// ---- P2 fused: zero-fill out + compact candidates (one streaming pass) ----
// Stores are PLAIN cached float4 (L2-acked; NT stores caused the r1 collapse
// by draining vmcnt at HBM latency). Stores are issued AFTER the batch loads
// so the load-consumer vmcnt(6) wait does not wait on them. Only LDS is the
// 8.7 KB staging block -> full occupancy (proven structure, r0/r3 ~62 us).
__global__ __launch_bounds__(256) void mainfill_kernel(
        const float4* __restrict__ in, float4* __restrict__ outv,
        const unsigned* __restrict__ res,
        float* __restrict__ cval, unsigned* __restrict__ cidx,
        unsigned* __restrict__ gcnt, unsigned cap, unsigned nvec) {
    __shared__ float    lval[LCAP];
    __shared__ unsigned lidx[LCAP];
    __shared__ unsigned lcnt, lbase;
    if (threadIdx.x == 0) lcnt = 0;
    __syncthreads();
    unsigned base = res[0];
    unsigned tid = blockIdx.x * 256 + threadIdx.x;
    unsigned nth = gridDim.x * 256;          // 524288; nvec/(6*nth) = 2 exact
    const float4 z4 = make_float4(0.f, 0.f, 0.f, 0.f);
    unsigned i0 = tid;
    unsigned nb = nvec / (MP_BATCH * nth);
    for (unsigned b = 0; b < nb; ++b) {
        float4 v[MP_BATCH];
        #pragma unroll
        for (int u = 0; u < MP_BATCH; ++u) v[u] = in[i0 + u * nth];  // 6 in flight
        #pragma unroll
        for (int u = 0; u < MP_BATCH; ++u) outv[i0 + u * nth] = z4;  // fused fill
        #pragma unroll
        for (int u = 0; u < MP_BATCH; ++u) {
            unsigned j = i0 + u * nth;
            unsigned idx = 4u * j;
            float xs[4] = {v[u].x, v[u].y, v[u].z, v[u].w};
            #pragma unroll
            for (int c = 0; c < 4; ++c) {
                unsigned key = f2key(xs[c]);
                if (key >= base) {                // ~1.7% taken
                    unsigned p = atomicAdd(&lcnt, 1u);
                    if (p < LCAP) { lval[p] = xs[c]; lidx[p] = idx + c; }
                    else {                        // overflow fallback
                        unsigned q = atomicAdd(gcnt, 1u);
                        if (q < cap) { cval[q] = xs[c]; cidx[q] = idx + c; }
                    }
                }
            }
        }
        i0 += MP_BATCH * nth;
    }
    for (; i0 < nvec; i0 += nth) {           // generic tail (empty here)
        float4 v = in[i0];
        outv[i0] = z4;
        unsigned idx = 4u * i0;
        float xs[4] = {v.x, v.y, v.z, v.w};
        #pragma unroll
        for (int c = 0; c < 4; ++c) {
            unsigned key = f2key(xs[c]);
            if (key >= base) {
                unsigned p = atomicAdd(&lcnt, 1u);
                if (p < LCAP) { lval[p] = xs[c]; lidx[p] = idx + c; }
                else {
                    unsigned q = atomicAdd(gcnt, 1u);
                    if (q < cap) { cval[q] = xs[c]; cidx[q] = idx + c; }
                }
            }
        }
    }
    __syncthreads();
    unsigned n = min(lcnt, (unsigned)LCAP);
    if (threadIdx.x == 0) lbase = atomicAdd(gcnt, n);
    __syncthreads();
    for (unsigned j = threadIdx.x; j < n; j += 256) {
        unsigned p = lbase + j;
        if (p < cap) { cval[p] = lval[j]; cidx[p] = lidx[j]; }
    }
}

// ---- CH+C2 fused: candidate histogram + ticketed last-block scan -> res2 --
__global__ __launch_bounds__(256) void candhist_findg_kernel(
        const float* __restrict__ cval, const unsigned* __restrict__ gcnt,
        const unsigned* __restrict__ res, unsigned* __restrict__ ghist,
        unsigned* __restrict__ done, unsigned* __restrict__ res2,
        unsigned cap) {
    __shared__ unsigned h[P2_BINS];           // 16 KB (reused by the scan)
    __shared__ unsigned psum[256];
    __shared__ unsigned lastS;
    int t = threadIdx.x;
    for (int i = t; i < P2_BINS; i += 256) h[i] = 0;
    __syncthreads();
    unsigned nc = min(*gcnt, cap);
    unsigned base = res[0];
    unsigned tid = blockIdx.x * 256 + t;
    unsigned nth = gridDim.x * 256;
    for (unsigned i0 = tid; i0 < nc; i0 += 4 * nth) {
        float v[4];
        #pragma unroll
        for (int u = 0; u < 4; ++u) {
            unsigned j = i0 + u * nth;
            v[u] = (j < nc) ? cval[j] : -1e30f;
        }
        #pragma unroll
        for (int u = 0; u < 4; ++u) {
            unsigned j = i0 + u * nth;
            if (j < nc) {
                unsigned g = (f2key(v[u]) - base) >> P2_SHIFT;
                if (g > P2_BINS - 1) g = P2_BINS - 1;
                atomicAdd(&h[g], 1u);
            }
        }
    }
    __syncthreads();
    for (int i = t; i < P2_BINS; i += 256) {
        unsigned c = h[i];
        if (c) atomicAdd(&ghist[i], c);
    }
    __threadfence();                          // release hist atomics
    __syncthreads();
    if (t == 0) {
        unsigned d = atomicAdd(done, 1u);
        lastS = (d == gridDim.x - 1) ? 1u : 0u;
    }
    __syncthreads();
    if (!lastS) return;                       // uniform per block

    for (int i = t; i < P2_BINS; i += 256) h[i] = atomicAdd(&ghist[i], 0u);
    __syncthreads();
    const int GB = P2_BINS / 256;             // 16 bins/thread, descending
    int hi = P2_BINS - 1 - t * GB;
    unsigned s = 0;
    #pragma unroll
    for (int j = 0; j < GB; ++j) s += h[hi - j];
    psum[t] = s;
    __syncthreads();
    for (int off = 1; off < 256; off <<= 1) {
        unsigned o = (t >= off) ? psum[t - off] : 0u;
        __syncthreads();
        psum[t] += o;
        __syncthreads();
    }
    unsigned cum = psum[t] - s;
    for (int j = 0; j < GB; ++j) {
        unsigned c = h[hi - j];
        if (cum < K_TOTAL && cum + c >= K_TOTAL) {
            res2[0] = (unsigned)(hi - j);     // g*
            res2[1] = K_TOTAL - cum;          // need2 inside bin g*
        }
        cum += c;
    }
}

// ---------------- C3: scatter definite winners, compact bin-g* -------------
__global__ __launch_bounds__(256) void scatter_kernel(
        const float* __restrict__ cval, const unsigned* __restrict__ cidx,
        const unsigned* __restrict__ gcnt, const unsigned* __restrict__ res,
        const unsigned* __restrict__ res2,
        float* __restrict__ cval2, unsigned* __restrict__ cidx2,
        unsigned* __restrict__ cnt2, unsigned cap,
        float* __restrict__ out) {
    unsigned nc = min(*gcnt, cap);
    unsigned base = res[0];
    unsigned gstar = res2[0];
    unsigned tid = blockIdx.x * 256 + threadIdx.x;
    unsigned nth = gridDim.x * 256;
    for (unsigned i0 = tid; i0 < nc; i0 += 4 * nth) {
        float v[4];
        #pragma unroll
        for (int u = 0; u < 4; ++u) {
            unsigned j = i0 + u * nth;
            v[u] = (j < nc) ? cval[j] : -1e30f;
        }
        #pragma unroll
        for (int u = 0; u < 4; ++u) {
            unsigned j = i0 + u * nth;
            if (j < nc) {
                unsigned g = (f2key(v[u]) - base) >> P2_SHIFT;
                if (g > P2_BINS - 1) g = P2_BINS - 1;
                if (g > gstar) {
                    out[cidx[j]] = fmaxf(v[u], 0.0f);    // definite winner
                } else if (g == gstar) {
                    unsigned p = atomicAdd(cnt2, 1u);
                    if (p < CAP2) { cval2[p] = v[u]; cidx2[p] = cidx[j]; }
                }
            }
        }
    }
}

// ---------------- C4: exact select in 4096-key range, ties, EMA ------------
__global__ __launch_bounds__(256) void final_kernel(
        const float* __restrict__ cval2, const unsigned* __restrict__ cidx2,
        const unsigned* __restrict__ cnt2,
        const unsigned* __restrict__ res, const unsigned* __restrict__ res2,
        float* __restrict__ out,
        const float* __restrict__ thr_in, float* __restrict__ thr_out) {
    __shared__ unsigned h[1 << P2_SHIFT];     // one bin per exact key
    __shared__ unsigned psum[256];
    __shared__ unsigned eqidx[EQCAP];
    __shared__ unsigned eqcnt;
    __shared__ unsigned sh_low, sh_need3;
    const int NB = 1 << P2_SHIFT;             // 4096
    int t = threadIdx.x;
    unsigned nc2   = min(*cnt2, CAP2);
    unsigned base3 = res[0] + (res2[0] << P2_SHIFT);
    unsigned need2 = res2[1];

    for (int i = t; i < NB; i += 256) h[i] = 0;
    if (t == 0) eqcnt = 0;
    __syncthreads();
    for (unsigned i = t; i < nc2; i += 256) {
        unsigned low = f2key(cval2[i]) - base3;
        if (low > (unsigned)(NB - 1)) low = NB - 1;
        atomicAdd(&h[low], 1u);
    }
    __syncthreads();

    const int GB = NB / 256;                  // 16 keys/thread, descending
    int hi = NB - 1 - t * GB;
    unsigned s = 0;
    for (int j = 0; j < GB; ++j) s += h[hi - j];
    psum[t] = s;
    __syncthreads();
    for (int off = 1; off < 256; off <<= 1) {
        unsigned o = (t >= off) ? psum[t - off] : 0u;
        __syncthreads();
        psum[t] += o;
        __syncthreads();
    }
    unsigned cum = psum[t] - s;
    for (int j = 0; j < GB; ++j) {
        unsigned c = h[hi - j];
        if (cum < need2 && cum + c >= need2) {
            sh_low = (unsigned)(hi - j);
            sh_need3 = need2 - cum;           // ties to accept at kth key
        }
        cum += c;
    }
    __syncthreads();
    unsigned kth_key = base3 + sh_low;
    unsigned need3   = sh_need3;

    for (unsigned i = t; i < nc2; i += 256) {
        float x = cval2[i];
        unsigned key = f2key(x);
        if (key > kth_key) {
            out[cidx2[i]] = fmaxf(x, 0.0f);
        } else if (key == kth_key) {
            unsigned p = atomicAdd(&eqcnt, 1u);
            if (p < EQCAP) eqidx[p] = cidx2[i];
        }
    }
    __syncthreads();

    // tie-break: lax.top_k picks lowest flat indices first
    unsigned ne = min(eqcnt, (unsigned)EQCAP);
    float vv = key2f(kth_key);
    for (unsigned e = t; e < ne; e += 256) {
        unsigned my = eqidx[e];
        unsigned rank = 0;
        for (unsigned f = 0; f < ne; ++f) rank += (eqidx[f] < my) ? 1u : 0u;
        if (rank < need3) out[my] = fmaxf(vv, 0.0f);
    }

    if (t == 0) {
        float mink = fmaxf(vv, 0.0f);         // relu(k-th largest)
        thr_out[0] = (1.0f - EMA_RATE) * thr_in[0] + EMA_RATE * mink;
    }
}

// ---------------- launch ----------------
extern "C" void kernel_launch(void* const* d_in, const int* in_sizes, int n_in,
                              void* d_out, int out_size, void* d_ws, size_t ws_size,
                              hipStream_t stream) {
    const float* feat   = (const float*)d_in[0];
    const float* thr_in = (const float*)d_in[1];
    float* out = (float*)d_out;
    int N    = in_sizes[0];      // 25165824
    int nvec = N / 4;

    // ---- workspace layout ----
    uint8_t* w = (uint8_t*)d_ws;
    unsigned* shist = (unsigned*)w;                        // 64 KB
    unsigned* ghist = (unsigned*)(w + (64 << 10));         // 16 KB
    unsigned* ctr   = (unsigned*)(w + (80 << 10));         // counters/res block
    unsigned* gcnt  = ctr + 0;
    unsigned* cnt2  = ctr + 1;
    unsigned* done1 = ctr + 2;    // sample ticket
    unsigned* done3 = ctr + 3;    // candhist ticket
    unsigned* res   = ctr + 4;    // res[0] = base key
    unsigned* res2  = ctr + 8;    // res2[0] = g*, res2[1] = need2

    size_t cand_off = (size_t)1 << 20;
    size_t avail    = (ws_size > cand_off + (CAP2 * 8 + 4096))
                        ? (ws_size - cand_off - CAP2 * 8 - 4096) / 8 : 0;
    unsigned cap = (unsigned)((avail < (size_t)(4u << 20)) ? avail : (size_t)(4u << 20));
    float*    cval  = (float*)(w + cand_off);
    unsigned* cidx  = (unsigned*)(w + cand_off + (size_t)cap * 4);
    float*    cval2 = (float*)(w + cand_off + (size_t)cap * 8);
    unsigned* cidx2 = (unsigned*)(w + cand_off + (size_t)cap * 8 + CAP2 * 4);

    // zero hists + counters only; output zeroing fused into mainfill
    hipMemsetAsync(d_ws, 0, (80 << 10) + 64, stream);

    sample_kernel       <<<SMP_BLOCKS, 256, 0, stream>>>((const float4*)feat,
                                                         shist, done1, res);
    mainfill_kernel     <<<MP_BLOCKS, 256, 0, stream>>>((const float4*)feat,
                                                        (float4*)out, res,
                                                        cval, cidx, gcnt, cap,
                                                        (unsigned)nvec);
    candhist_findg_kernel<<<128, 256, 0, stream>>>(cval, gcnt, res, ghist,
                                                   done3, res2, cap);
    scatter_kernel      <<<128, 256, 0, stream>>>(cval, cidx, gcnt, res, res2,
                                                  cval2, cidx2, cnt2, cap, out);
    final_kernel        <<<1,   256, 0, stream>>>(cval2, cidx2, cnt2, res, res2,
                                                  out, thr_in, out + N);
}